// Round 3
// baseline (1147.939 us; speedup 1.0000x reference)
//
#include <hip/hip_runtime.h>

// 16-qubit, depth-4, batch-512 statevector simulator — register-resident,
// L3-blocked version.
// State: 512 x 65536 complex64 = 256 MiB in d_ws.
// Batches are independent -> process NGROUPS=4 groups of 128 batches, running
// all 8 passes per group back-to-back so the group's 64 MiB state stays
// L3-resident across passes (per-pass working set 128 MiB << 256 MiB L3).
//
// Reference qubit q <-> flat-index bit beta = 15-q.
// Memory layout per batch: amp with basis index g stored at m = (g>>3) | ((g&7)<<13).
//
// passA (window = g bits 3..15 as local j bits 0..12; fix3 = g bits 0..2):
//   Each thread holds 32 amps in registers. Ownership arrangements:
//     arr1 {0,9,10,11,12} (qubits 12,3,2,1,0) -> transpose -> arr2 {1,2,3,4,12}
//     (qubits 11,10,9,8) -> transpose -> arr3 {5,6,7,8,12} (qubits 7,6,5,4)
//   Writeback folds the 12-CNOT chain perm final[j] = S[j ^ ((j>>1)&0xFFF)].
//   Transposes staged through a 32 KB LDS buffer in 2 rounds split by bit 12.
//   LDS slot swizzle: slot(j) = j ^ (((j>>5)&7)<<1).
// passB (3 gates on local bits 10,11,12 = qubits 15,14,13 + CNOT tail perm):
//   perm i = d ^ ((d>>1)&0x0E00) ^ ((d&1)<<12) only mixes thread-owned bits
//   {0,9..12} => pure register kernel. U matrices computed redundantly per
//   thread: ZERO LDS, ZERO barriers, no vmcnt(0) drain between load and math.
// Layer-0 passA generates the RX product state analytically in registers.
// Layer-3 passB computes expZ (signs read off dest-index bits) + atomicAdd.

#define NQ 16
#define TPB 256
#define NGROUPS 4
#define GB (512 / NGROUPS)   // batches per group

typedef float2 cplx;

__device__ __forceinline__ cplx cmadd2(cplx u, cplx a, cplx v, cplx b) {
    return make_float2(u.x*a.x - u.y*a.y + v.x*b.x - v.y*b.y,
                       u.x*a.y + u.y*a.x + v.x*b.y + v.y*b.x);
}

// U = RY(t2) * RX(t1) * RZ(t0), row-major [u00,u01,u10,u11]
__device__ __forceinline__ void computeU(const float* params, int layer, int q, cplx* U) {
    const float* p = params + (layer*NQ + q)*3;
    float s0, c0, s1, c1, s2, c2;
    sincosf(0.5f*p[0], &s0, &c0);
    sincosf(0.5f*p[1], &s1, &c1);
    sincosf(0.5f*p[2], &s2, &c2);
    cplx m00 = make_float2( c1*c0, -c1*s0);
    cplx m01 = make_float2( s1*s0, -s1*c0);
    cplx m10 = make_float2(-s1*s0, -s1*c0);
    cplx m11 = make_float2( c1*c0,  c1*s0);
    U[0] = make_float2(c2*m00.x - s2*m10.x, c2*m00.y - s2*m10.y);
    U[1] = make_float2(c2*m01.x - s2*m11.x, c2*m01.y - s2*m11.y);
    U[2] = make_float2(s2*m00.x + c2*m10.x, s2*m00.y + c2*m10.y);
    U[3] = make_float2(s2*m01.x + c2*m11.x, s2*m01.y + c2*m11.y);
}

// 1q gate on register array A[32], pairing a <-> a|MASK (MASK = in-thread bit).
template<int MASK>
__device__ __forceinline__ void gate32(cplx* A, cplx u00, cplx u01, cplx u10, cplx u11) {
    #pragma unroll
    for (int a = 0; a < 32; ++a) {
        if (!(a & MASK)) {
            cplx xx = A[a], yy = A[a | MASK];
            A[a]        = cmadd2(u00, xx, u01, yy);
            A[a | MASK] = cmadd2(u10, xx, u11, yy);
        }
    }
}

// passB register perm: dest reg ad -> source reg (bits: i0=d0, i9=d9^d10,
// i10=d10^d11, i11=d11^d12, i12=d12^d0; reg bits = (d0, d9..d12)).
__device__ __forceinline__ constexpr int permB(int ad) {
    return (ad & 1)
         | ((((ad >> 1) ^ (ad >> 2)) & 1) << 1)
         | ((((ad >> 2) ^ (ad >> 3)) & 1) << 2)
         | ((((ad >> 3) ^ (ad >> 4)) & 1) << 3)
         | ((((ad >> 4) ^  ad      ) & 1) << 4);
}

__global__ __launch_bounds__(TPB) void qc_passA(
    const float* __restrict__ x, const float* __restrict__ params,
    float2* __restrict__ st, int layer, int first, int bofs)
{
    __shared__ __align__(16) float2 S[4096];   // 32 KB, one bit-12 half at a time
    __shared__ cplx Ush[13][4];
    __shared__ float cb[NQ], sb[NQ];

    const int t    = threadIdx.x;
    const int b    = bofs + (blockIdx.x >> 3);
    const int fix3 = blockIdx.x & 7;            // g bits 0..2
    float2* base = st + ((size_t)b << NQ) + (fix3 << 13);

    if (t < 13) computeU(params, layer, 12 - t, Ush[t]);

    // arr1: register a = o | (k<<1); j = o | (t<<1) | (k<<9); owned j bits {0,9,10,11,12}
    cplx A[32];
    if (first) {
        if (t < NQ) {                            // g bit beta = t, qubit 15-t
            float hh = 0.5f * x[b*NQ + (15 - t)];
            sb[t] = sinf(hh); cb[t] = cosf(hh);
        }
        __syncthreads();
        // fixed factors: g bits 0..2 = fix3, g bits 4..11 = t
        float pf = 1.f;
        #pragma unroll
        for (int bet = 0; bet < 3; ++bet) pf *= ((fix3 >> bet) & 1) ? sb[bet] : cb[bet];
        #pragma unroll
        for (int bet = 4; bet < 12; ++bet) pf *= ((t >> (bet - 4)) & 1) ? sb[bet] : cb[bet];
        int pcT = __popc(fix3) + __popc(t & 255);
        #pragma unroll
        for (int a = 0; a < 32; ++a) {
            // g bit 3 = a&1, g bits 12..15 = a>>1
            float r = pf * ((a & 1) ? sb[3] : cb[3]);
            r *= (((a >> 1) & 1) ? sb[12] : cb[12]);
            r *= (((a >> 2) & 1) ? sb[13] : cb[13]);
            r *= (((a >> 3) & 1) ? sb[14] : cb[14]);
            r *= (((a >> 4) & 1) ? sb[15] : cb[15]);
            int pc = (pcT + __popc(a)) & 3;      // phase (-i)^pc
            float re = (pc == 0) ? r : ((pc == 2) ? -r : 0.f);
            float im = (pc == 1) ? -r : ((pc == 3) ? r : 0.f);
            A[a] = make_float2(re, im);
        }
    } else {
        const float4* src = (const float4*)base;
        #pragma unroll
        for (int k = 0; k < 16; ++k) {
            float4 v = src[t + 256*k];           // amps j = 2(t+256k)+{0,1}
            A[2*k]   = make_float2(v.x, v.y);
            A[2*k+1] = make_float2(v.z, v.w);
        }
    }
    __syncthreads();                             // Ush (and cb/sb) ready

    // arr1 gates: j0 -> qubit 12 (Ush[0]); j9,j10,j11,j12 -> qubits 3,2,1,0
    gate32<1> (A, Ush[0][0],  Ush[0][1],  Ush[0][2],  Ush[0][3]);
    gate32<2> (A, Ush[9][0],  Ush[9][1],  Ush[9][2],  Ush[9][3]);
    gate32<4> (A, Ush[10][0], Ush[10][1], Ush[10][2], Ush[10][3]);
    gate32<8> (A, Ush[11][0], Ush[11][1], Ush[11][2], Ush[11][3]);
    gate32<16>(A, Ush[12][0], Ush[12][1], Ush[12][2], Ush[12][3]);

    // Transpose 1: arr1 -> arr2 {1,2,3,4,12}; rounds by bit 12 (= reg bit 4)
    #pragma unroll
    for (int h = 0; h < 2; ++h) {
        __syncthreads();
        #pragma unroll
        for (int c = 0; c < 8; ++c) {            // write pairs: j' = (t<<1)|(c<<9)
            int slot = ((t << 1) | (c << 9)) ^ (((t >> 4) & 7) << 1);
            cplx a0 = A[h*16 + 2*c], a1 = A[h*16 + 2*c + 1];
            *(float4*)&S[slot] = make_float4(a0.x, a0.y, a1.x, a1.y);
        }
        __syncthreads();
        #pragma unroll
        for (int rr = 0; rr < 16; ++rr) {        // read arr2: j bits1..4 = rr
            int jj = (t & 1) | (rr << 1) | (((t >> 1) & 15) << 5) | (((t >> 5) & 7) << 9);
            A[h*16 + rr] = S[jj ^ (((t >> 1) & 7) << 1)];
        }
    }

    // arr2 gates: j1..j4 -> qubits 11,10,9,8 (Ush[1..4])
    gate32<1>(A, Ush[1][0], Ush[1][1], Ush[1][2], Ush[1][3]);
    gate32<2>(A, Ush[2][0], Ush[2][1], Ush[2][2], Ush[2][3]);
    gate32<4>(A, Ush[3][0], Ush[3][1], Ush[3][2], Ush[3][3]);
    gate32<8>(A, Ush[4][0], Ush[4][1], Ush[4][2], Ush[4][3]);

    // Transpose 2: arr2 -> arr3 {5,6,7,8,12}
    #pragma unroll
    for (int h = 0; h < 2; ++h) {
        __syncthreads();
        #pragma unroll
        for (int rr = 0; rr < 16; ++rr) {        // write at arr2 positions
            int jj = (t & 1) | (rr << 1) | (((t >> 1) & 15) << 5) | (((t >> 5) & 7) << 9);
            S[jj ^ (((t >> 1) & 7) << 1)] = A[h*16 + rr];
        }
        __syncthreads();
        #pragma unroll
        for (int rr = 0; rr < 16; ++rr) {        // read arr3: j bits5..8 = rr
            int jj = (t & 31) | (rr << 5) | (((t >> 5) & 7) << 9);
            A[h*16 + rr] = S[jj ^ ((rr & 7) << 1)];
        }
    }

    // arr3 gates: j5..j8 -> qubits 7,6,5,4 (Ush[5..8])
    gate32<1>(A, Ush[5][0], Ush[5][1], Ush[5][2], Ush[5][3]);
    gate32<2>(A, Ush[6][0], Ush[6][1], Ush[6][2], Ush[6][3]);
    gate32<4>(A, Ush[7][0], Ush[7][1], Ush[7][2], Ush[7][3]);
    gate32<8>(A, Ush[8][0], Ush[8][1], Ush[8][2], Ush[8][3]);

    // Writeback: stage at natural slots, read with CNOT-chain perm, store coalesced
    float4* dst = (float4*)base;
    #pragma unroll
    for (int h = 0; h < 2; ++h) {
        __syncthreads();
        #pragma unroll
        for (int rr = 0; rr < 16; ++rr) {        // write at natural (arr3) positions
            int jj = (t & 31) | (rr << 5) | (((t >> 5) & 7) << 9);
            S[jj ^ ((rr & 7) << 1)] = A[h*16 + rr];
        }
        __syncthreads();
        #pragma unroll
        for (int k = 0; k < 8; ++k) {            // dest d' = 2(t+256k), bit12 = h
            int d  = 2*(t + 256*k);
            int i0 = d ^ (d >> 1) ^ (h << 11);           // source (12-bit)
            int i1 = (d+1) ^ ((d+1) >> 1) ^ (h << 11);
            cplx a0 = S[i0 ^ (((i0 >> 5) & 7) << 1)];
            cplx a1 = S[i1 ^ (((i1 >> 5) & 7) << 1)];
            dst[(t + 256*k) | (h << 11)] = make_float4(a0.x, a0.y, a1.x, a1.y);
        }
    }
}

__global__ __launch_bounds__(TPB) void qc_passB(
    const float* __restrict__ params, float2* __restrict__ st,
    float* __restrict__ out, int layer, int last, int bofs)
{
    const int t    = threadIdx.x;
    const int b    = bofs + (blockIdx.x >> 3);
    const int fixb = blockIdx.x & 7;             // g bits 12..14
    float2* base = st + ((size_t)b << NQ);

    // local d: bits 0..8 = g bits 3..11, bit 9 = g bit 15, bits 10..12 = g bits 0..2
    // U matrices in registers (redundant per thread; no LDS, no barrier)
    cplx U15[4], U14[4], U13[4];
    computeU(params, layer, 15, U15);
    computeU(params, layer, 14, U14);
    computeU(params, layer, 13, U13);

    // registers: a = d0 | (k<<1) where k = d bits 9..12; thread owns {0,9,10,11,12}
    cplx A[32];
    #pragma unroll
    for (int k = 0; k < 16; ++k) {
        int j = 2*(t + 256*k);
        int m = (j & 511) | (fixb << 9) | (((j >> 9) & 1) << 12) | ((j >> 10) << 13);
        float4 v = *(const float4*)(base + m);
        A[2*k]   = make_float2(v.x, v.y);
        A[2*k+1] = make_float2(v.z, v.w);
    }

    // gates: d10 (q15) = reg bit 2; d11 (q14) = bit 3; d12 (q13) = bit 4
    gate32<4> (A, U15[0], U15[1], U15[2], U15[3]);
    gate32<8> (A, U14[0], U14[1], U14[2], U14[3]);
    gate32<16>(A, U13[0], U13[1], U13[2], U13[3]);

    if (!last) {
        // store with CNOT-tail perm folded (register-internal)
        #pragma unroll
        for (int k = 0; k < 16; ++k) {
            int j = 2*(t + 256*k);
            int m = (j & 511) | (fixb << 9) | (((j >> 9) & 1) << 12) | ((j >> 10) << 13);
            cplx a0 = A[permB(2*k)];
            cplx a1 = A[permB(2*k + 1)];
            *(float4*)(base + m) = make_float4(a0.x, a0.y, a1.x, a1.y);
        }
    } else {
        // expZ epilogue: signs from dest reg index ad:
        // ad0 = g3, ad1 = g15, ad2 = g0, ad3 = g1, ad4 = g2
        float accT = 0.f, sg3 = 0.f, sg15 = 0.f, sg0 = 0.f, sg1 = 0.f, sg2 = 0.f;
        #pragma unroll
        for (int ad = 0; ad < 32; ++ad) {
            cplx v = A[permB(ad)];
            float p = v.x*v.x + v.y*v.y;
            accT += p;
            sg3  += (ad & 1)  ? -p : p;
            sg15 += (ad & 2)  ? -p : p;
            sg0  += (ad & 4)  ? -p : p;
            sg1  += (ad & 8)  ? -p : p;
            sg2  += (ad & 16) ? -p : p;
        }
        float acc[NQ];
        #pragma unroll
        for (int q = 0; q < NQ; ++q) {
            int beta = 15 - q;
            float v;
            if      (beta == 15) v = sg15;
            else if (beta == 0)  v = sg0;
            else if (beta == 1)  v = sg1;
            else if (beta == 2)  v = sg2;
            else if (beta == 3)  v = sg3;
            else if (beta <= 11) v = ((t >> (beta - 4)) & 1) ? -accT : accT;   // g4..11 = t
            else                 v = ((fixb >> (beta - 12)) & 1) ? -accT : accT;
            acc[q] = v;
        }
        #pragma unroll
        for (int q = 0; q < NQ; ++q) {
            float v = acc[q];
            v += __shfl_down(v, 32, 64);
            v += __shfl_down(v, 16, 64);
            v += __shfl_down(v,  8, 64);
            v += __shfl_down(v,  4, 64);
            v += __shfl_down(v,  2, 64);
            v += __shfl_down(v,  1, 64);
            acc[q] = v;
        }
        if ((t & 63) == 0) {
            #pragma unroll
            for (int q = 0; q < NQ; ++q)
                atomicAdd(&out[b*NQ + q], acc[q]);
        }
    }
}

extern "C" void kernel_launch(void* const* d_in, const int* in_sizes, int n_in,
                              void* d_out, int out_size, void* d_ws, size_t ws_size,
                              hipStream_t stream)
{
    (void)in_sizes; (void)n_in; (void)ws_size;
    const float* x      = (const float*)d_in[0];   // (512,16) fp32
    const float* params = (const float*)d_in[1];   // (4,16,3) fp32
    float* out = (float*)d_out;                    // (512,16) fp32
    float2* st = (float2*)d_ws;                    // 256 MiB state

    hipMemsetAsync(d_out, 0, (size_t)out_size * sizeof(float), stream);
    // Batch-grouped so each group's 64 MiB state stays L3-resident across its
    // 8 passes (per-pass working set 128 MiB << 256 MiB L3).
    for (int g = 0; g < NGROUPS; ++g) {
        int bofs = g * GB;
        for (int l = 0; l < 4; ++l) {
            qc_passA<<<dim3(GB*8), dim3(TPB), 0, stream>>>(x, params, st, l, (l == 0) ? 1 : 0, bofs);
            qc_passB<<<dim3(GB*8), dim3(TPB), 0, stream>>>(params, st, out, l, (l == 3) ? 1 : 0, bofs);
        }
    }
}